// Round 1
// baseline (797.455 us; speedup 1.0000x reference)
//
#include <hip/hip_runtime.h>

// Problem constants (fixed by setup_inputs)
#define BG    4        // num_graphs
#define TT    12       // timesteps
#define NN    10000    // nodes per graph
#define EN    200000   // membership entries
#define NSEG  40000    // n*B segments
#define NROWS 40000    // B*n output rows
#define MPAD  40064    // 313*128
#define KD    800      // padded in_dim (780 -> 800 = 25*32)
#define NPW   896      // padded N for weight tiles (7*128)

typedef __attribute__((ext_vector_type(8))) short bf8_t;   // 8 bf16 (4 VGPR) MFMA A/B frag
typedef __attribute__((ext_vector_type(4))) float f4_t;    // 4 f32 MFMA C/D frag

__device__ __forceinline__ unsigned short f2bf(float x) {  // RNE f32->bf16
  unsigned int u = __float_as_uint(x);
  u += 0x7fffu + ((u >> 16) & 1u);
  return (unsigned short)(u >> 16);
}

#define GLDS16(src, dst) __builtin_amdgcn_global_load_lds( \
    (const __attribute__((address_space(1))) void*)(src),  \
    (__attribute__((address_space(3))) void*)(dst), 16, 0, 0)

// ---------------- prep: CSR of (segment -> batch ids) ----------------
__global__ void k_zero(int* counts) {
  int i = blockIdx.x * 256 + threadIdx.x;
  if (i < NSEG) counts[i] = 0;
}

__global__ void k_count(const int* __restrict__ mapper, int* __restrict__ counts) {
  int e = blockIdx.x * 256 + threadIdx.x;
  if (e < EN) atomicAdd(&counts[mapper[e]], 1);
}

__global__ __launch_bounds__(1024) void k_scan(const int* __restrict__ counts,
                                               int* __restrict__ offs,
                                               int* __restrict__ cursor) {
  __shared__ int sd[1024];
  const int t = threadIdx.x;
  int loc[40];
  int sum = 0;
  #pragma unroll
  for (int i = 0; i < 40; ++i) {
    int idx = t * 40 + i;
    int v = (idx < NSEG) ? counts[idx] : 0;
    loc[i] = sum;
    sum += v;
  }
  sd[t] = sum;
  __syncthreads();
  for (int off = 1; off < 1024; off <<= 1) {
    int v = (t >= off) ? sd[t - off] : 0;
    __syncthreads();
    sd[t] += v;
    __syncthreads();
  }
  const int ebase = sd[t] - sum;  // exclusive prefix for this thread's chunk
  #pragma unroll
  for (int i = 0; i < 40; ++i) {
    int idx = t * 40 + i;
    if (idx < NSEG) { int o = ebase + loc[i]; offs[idx] = o; cursor[idx] = o; }
  }
}

__global__ void k_scatter(const int* __restrict__ mapper, const int* __restrict__ batch,
                          int* __restrict__ cursor, int* __restrict__ sorted) {
  int e = blockIdx.x * 256 + threadIdx.x;
  if (e < EN) {
    int s = mapper[e];
    int pos = atomicAdd(&cursor[s], 1);
    sorted[pos] = batch[e];
  }
}

// ---------------- weight prep ----------------
// Wt[n][k] = W[k][n], zero-padded to [Nrows][KD] bf16. W is [780][ldw].
__global__ void k_tpad(const float* __restrict__ W, unsigned short* __restrict__ Wt,
                       int ldw, int nsrc, int total) {
  int idx = blockIdx.x * 256 + threadIdx.x;
  if (idx >= total) return;
  int n = idx / KD, k = idx % KD;
  float v = (n < nsrc && k < 780) ? W[k * ldw + n] : 0.f;
  Wt[idx] = f2bf(v);
}

__global__ void k_padbias(const float* __restrict__ b1, const float* __restrict__ b2,
                          float* __restrict__ p1, float* __restrict__ p2) {
  int i = blockIdx.x * 256 + threadIdx.x;
  if (i < KD) p1[i] = (i < 780) ? b1[i] : 0.f;
  else if (i < 2 * KD) { int c = i - KD; p2[c] = (c < 780) ? b2[c] : 0.f; }
}

// flatW0[j][c] = sum_k flat[j][k] * W0[12+k][c], j<128, c<780 (0 for 780<=c<800)
// flat[j][t*64+f] = mixer_x[j%4][t][j/4][f]
__global__ __launch_bounds__(256) void k_flatW0(const float* __restrict__ mixer,
                                                const float* __restrict__ W0,
                                                float* __restrict__ fW0) {
  __shared__ float srow[768];
  const int j = blockIdx.x, tid = threadIdx.x;
  for (int i = tid; i < 768; i += 256) {
    int tt = i >> 6, ff = i & 63;
    srow[i] = mixer[(((j & 3) * TT + tt) * 32 + (j >> 2)) * 64 + ff];
  }
  __syncthreads();
  for (int c = tid; c < KD; c += 256) {
    float acc = 0.f;
    if (c < 780) {
      #pragma unroll 4
      for (int k = 0; k < 768; ++k) acc = fmaf(srow[k], W0[(12 + k) * 780 + c], acc);
    }
    fW0[j * KD + c] = acc;
  }
}

// ---------------- layer 0 (sparse mean of flatW0 rows + passthrough GEMV) ----------------
__global__ __launch_bounds__(256) void k_layer0(
    const float* __restrict__ features, const int* __restrict__ counts,
    const int* __restrict__ offs, const int* __restrict__ sorted,
    const float* __restrict__ fW0, const float* __restrict__ W0,
    const float* __restrict__ b0, unsigned short* __restrict__ h0) {
  __shared__ float sW0[12 * KD];   // passthrough weights, padded
  const int tid = threadIdx.x, lane = tid & 63, wid = tid >> 6;
  for (int tt = 0; tt < 12; ++tt)
    for (int c = tid; c < KD; c += 256)
      sW0[tt * KD + c] = (c < 780) ? W0[tt * 780 + c] : 0.f;
  __syncthreads();

  float bcol[13];
  #pragma unroll
  for (int cc = 0; cc < 13; ++cc) {
    int col = cc * 64 + lane;
    bcol[cc] = (col < 780) ? b0[col] : 0.f;
  }

  for (int i = 0; i < 32; ++i) {
    const int r = blockIdx.x * 128 + wid * 32 + i;
    unsigned short* hr = h0 + (size_t)r * KD;
    if (r < NROWS) {
      const int s = (r % NN) * BG + (r / NN);
      const int cnt = counts[s];
      const int e0 = offs[s];
      float acc[13];
      #pragma unroll
      for (int cc = 0; cc < 13; ++cc) acc[cc] = 0.f;
      for (int e = e0; e < e0 + cnt; ++e) {
        const int j = sorted[e];                    // wave-uniform broadcast load
        const float* fw = fW0 + j * KD;
        #pragma unroll
        for (int cc = 0; cc < 13; ++cc) {
          int col = cc * 64 + lane;
          if (col < KD) acc[cc] += fw[col];
        }
      }
      const float inv = 1.f / (float)(cnt > 0 ? cnt : 1);
      #pragma unroll
      for (int cc = 0; cc < 13; ++cc) acc[cc] *= inv;
      const float* fr = features + (size_t)r * TT;
      #pragma unroll
      for (int t2 = 0; t2 < 12; ++t2) {
        const float ft = fr[t2];
        #pragma unroll
        for (int cc = 0; cc < 13; ++cc) {
          int col = cc * 64 + lane;
          if (col < KD) acc[cc] = fmaf(ft, sW0[t2 * KD + col], acc[cc]);
        }
      }
      #pragma unroll
      for (int cc = 0; cc < 13; ++cc) {
        int col = cc * 64 + lane;
        if (col < KD) hr[col] = f2bf(fmaxf(acc[cc] + bcol[cc], 0.f));
      }
    } else {  // pad rows 40000..40063: clean zeros for the GEMM
      #pragma unroll
      for (int cc = 0; cc < 13; ++cc) {
        int col = cc * 64 + lane;
        if (col < KD) hr[col] = 0;
      }
    }
  }
}

// ---------------- dense layers: C = relu(A @ W + b), bf16 MFMA ----------------
// A [MPAD][KD] bf16, WT [NPW][KD] bf16 (= W transposed, padded), C [MPAD][KD] bf16.
// m97 structure: 128x128 tile, BK=32, 4 waves (2x2), global_load_lds w=16.
// SWAPPED operands: mfma(Wfrag, Afrag, acc) -> lane holds 4 consecutive output
// COLUMNS (packed 8B bf16 stores) at output row = lane&15.
__global__ __launch_bounds__(256) void gemm_relu(
    const unsigned short* __restrict__ A, const unsigned short* __restrict__ WT,
    const float* __restrict__ bias, unsigned short* __restrict__ C) {
  __shared__ unsigned short sA[128 * 32];
  __shared__ unsigned short sB[128 * 32];
  const int tid = threadIdx.x, lane = tid & 63, wid = tid >> 6;
  const int wm = wid >> 1, wn = wid & 1;
  const int row0 = blockIdx.x * 128, n0 = blockIdx.y * 128;
  const char* gA = (const char*)A + (size_t)row0 * (KD * 2);
  const char* gB = (const char*)WT + (size_t)n0 * (KD * 2);
  const int frow = lane & 15, fk = (lane >> 4) * 8;

  f4_t acc[4][4] = {};

  for (int kt = 0; kt < 25; ++kt) {
    const int kb = kt * 64;  // byte offset of 32-element K chunk
    __syncthreads();
    #pragma unroll
    for (int L = 0; L < 2; ++L) {
      const int segb = L * 256 + wid * 64;
      const int seg = segb + lane;
      const size_t go = (size_t)(seg >> 2) * (KD * 2) + kb + (seg & 3) * 16;
      GLDS16(gA + go, (char*)sA + segb * 16);
      GLDS16(gB + go, (char*)sB + segb * 16);
    }
    __syncthreads();
    bf8_t af[4], bf[4];
    #pragma unroll
    for (int mi = 0; mi < 4; ++mi)
      af[mi] = *(const bf8_t*)(sA + (wm * 64 + mi * 16 + frow) * 32 + fk);
    #pragma unroll
    for (int ni = 0; ni < 4; ++ni)
      bf[ni] = *(const bf8_t*)(sB + (wn * 64 + ni * 16 + frow) * 32 + fk);
    #pragma unroll
    for (int mi = 0; mi < 4; ++mi)
      #pragma unroll
      for (int ni = 0; ni < 4; ++ni)
        acc[mi][ni] = __builtin_amdgcn_mfma_f32_16x16x32_bf16(bf[ni], af[mi], acc[mi][ni], 0, 0, 0);
  }

  const int cq = (lane >> 4) * 4;
  #pragma unroll
  for (int mi = 0; mi < 4; ++mi) {
    const int r = row0 + wm * 64 + mi * 16 + frow;
    unsigned short* crow = C + (size_t)r * KD;
    #pragma unroll
    for (int ni = 0; ni < 4; ++ni) {
      const int c = n0 + wn * 64 + ni * 16 + cq;
      if (c < KD) {  // wave-uniform per fragment
        f4_t v = acc[mi][ni];
        const f4_t bb = *(const f4_t*)(bias + c);
        float v0 = fmaxf(v[0] + bb[0], 0.f);
        float v1 = fmaxf(v[1] + bb[1], 0.f);
        float v2 = fmaxf(v[2] + bb[2], 0.f);
        float v3 = fmaxf(v[3] + bb[3], 0.f);
        uint2 pk;
        pk.x = (unsigned int)f2bf(v0) | ((unsigned int)f2bf(v1) << 16);
        pk.y = (unsigned int)f2bf(v2) | ((unsigned int)f2bf(v3) << 16);
        *(uint2*)(crow + c) = pk;
      }
    }
  }
}

// ---------------- final layer: out = A @ W3 + b3 (N=16 padded, write 12 cols f32) ----------
__global__ __launch_bounds__(256) void gemm_out(
    const unsigned short* __restrict__ A, const unsigned short* __restrict__ WT3,
    const float* __restrict__ b3, float* __restrict__ out) {
  __shared__ unsigned short sA[128 * 32];
  __shared__ unsigned short sB[16 * 32];
  const int tid = threadIdx.x, lane = tid & 63, wid = tid >> 6;
  const int row0 = blockIdx.x * 128;
  const char* gA = (const char*)A + (size_t)row0 * (KD * 2);
  const char* gB = (const char*)WT3;
  const int frow = lane & 15, fk = (lane >> 4) * 8;

  f4_t acc[2] = {};

  for (int kt = 0; kt < 25; ++kt) {
    const int kb = kt * 64;
    __syncthreads();
    #pragma unroll
    for (int L = 0; L < 2; ++L) {
      const int segb = L * 256 + wid * 64;
      const int seg = segb + lane;
      GLDS16(gA + (size_t)(seg >> 2) * (KD * 2) + kb + (seg & 3) * 16, (char*)sA + segb * 16);
    }
    if (wid == 0) {
      const int seg = lane;  // 16 rows x 32 K = 64 x 16B
      GLDS16(gB + (size_t)(seg >> 2) * (KD * 2) + kb + (seg & 3) * 16, (char*)sB);
    }
    __syncthreads();
    const bf8_t bf = *(const bf8_t*)(sB + frow * 32 + fk);
    #pragma unroll
    for (int mi = 0; mi < 2; ++mi) {
      const bf8_t af = *(const bf8_t*)(sA + (wid * 32 + mi * 16 + frow) * 32 + fk);
      acc[mi] = __builtin_amdgcn_mfma_f32_16x16x32_bf16(bf, af, acc[mi], 0, 0, 0);
    }
  }

  const int cg = (lane >> 4) * 4;
  #pragma unroll
  for (int mi = 0; mi < 2; ++mi) {
    const int r = row0 + wid * 32 + mi * 16 + frow;
    if (r < NROWS && cg < 12) {
      f4_t v = acc[mi];
      const f4_t bb = *(const f4_t*)(b3 + cg);  // cg in {0,4,8}: reads b3[0..11]
      v += bb;
      *(f4_t*)(out + (size_t)r * 12 + cg) = v;
    }
  }
}

// ---------------- host ----------------
extern "C" void kernel_launch(void* const* d_in, const int* in_sizes, int n_in,
                              void* d_out, int out_size, void* d_ws, size_t ws_size,
                              hipStream_t stream) {
  const float* mixer    = (const float*)d_in[0];
  const float* features = (const float*)d_in[1];
  const int*   sg_batch = (const int*)d_in[2];
  const int*   sg_map   = (const int*)d_in[3];
  const float* W0 = (const float*)d_in[4];  const float* b0 = (const float*)d_in[5];
  const float* W1 = (const float*)d_in[6];  const float* b1 = (const float*)d_in[7];
  const float* W2 = (const float*)d_in[8];  const float* b2 = (const float*)d_in[9];
  const float* W3 = (const float*)d_in[10]; const float* b3 = (const float*)d_in[11];
  float* out = (float*)d_out;

  char* wsp = (char*)d_ws;
  auto alloc = [&](size_t bytes) { char* p = wsp; wsp += (bytes + 255) & ~(size_t)255; return p; };
  unsigned short* h0  = (unsigned short*)alloc((size_t)MPAD * KD * 2);   // 64.1 MB
  unsigned short* h1  = (unsigned short*)alloc((size_t)MPAD * KD * 2);   // 64.1 MB
  unsigned short* Wt1 = (unsigned short*)alloc((size_t)NPW * KD * 2);
  unsigned short* Wt2 = (unsigned short*)alloc((size_t)NPW * KD * 2);
  unsigned short* Wt3 = (unsigned short*)alloc((size_t)16 * KD * 2);
  float* bp1   = (float*)alloc(KD * 4);
  float* bp2   = (float*)alloc(KD * 4);
  float* fW0   = (float*)alloc((size_t)128 * KD * 4);
  int* counts  = (int*)alloc(NSEG * 4);
  int* offs    = (int*)alloc(NSEG * 4);
  int* cursor  = (int*)alloc(NSEG * 4);
  int* sorted  = (int*)alloc(EN * 4);

  // CSR build
  k_zero<<<(NSEG + 255) / 256, 256, 0, stream>>>(counts);
  k_count<<<(EN + 255) / 256, 256, 0, stream>>>(sg_map, counts);
  k_scan<<<1, 1024, 0, stream>>>(counts, offs, cursor);
  k_scatter<<<(EN + 255) / 256, 256, 0, stream>>>(sg_map, sg_batch, cursor, sorted);

  // weight prep
  k_tpad<<<(NPW * KD + 255) / 256, 256, 0, stream>>>(W1, Wt1, 780, 780, NPW * KD);
  k_tpad<<<(NPW * KD + 255) / 256, 256, 0, stream>>>(W2, Wt2, 780, 780, NPW * KD);
  k_tpad<<<(16 * KD + 255) / 256, 256, 0, stream>>>(W3, Wt3, 12, 12, 16 * KD);
  k_padbias<<<7, 256, 0, stream>>>(b1, b2, bp1, bp2);
  k_flatW0<<<128, 256, 0, stream>>>(mixer, W0, fW0);

  // layer 0 (sparse) -> h0
  k_layer0<<<MPAD / 128, 256, 0, stream>>>(features, counts, offs, sorted, fW0, W0, b0, h0);

  // layers 1,2 (dense bf16 MFMA) -> h1 -> h0
  gemm_relu<<<dim3(MPAD / 128, NPW / 128), 256, 0, stream>>>(h0, Wt1, bp1, h1);
  gemm_relu<<<dim3(MPAD / 128, NPW / 128), 256, 0, stream>>>(h1, Wt2, bp2, h0);

  // layer 3 -> out
  gemm_out<<<MPAD / 128, 256, 0, stream>>>(h0, Wt3, b3, out);
}

// Round 3
// 584.851 us; speedup vs baseline: 1.3635x; 1.3635x over previous
//
#include <hip/hip_runtime.h>

// Problem constants (fixed by setup_inputs)
#define BG    4        // num_graphs
#define TT    12       // timesteps
#define NN    10000    // nodes per graph
#define EN    200000   // membership entries
#define NSEG  40000    // n*B segments
#define NROWS 40000    // B*n output rows
#define MPAD  40064    // 313*128
#define KD    800      // padded in_dim (780 -> 800 = 25*32)
#define NPW   896      // padded N for weight tiles (7*128)

typedef __attribute__((ext_vector_type(8))) short bf8_t;   // 8 bf16 (4 VGPR) MFMA A/B frag
typedef __attribute__((ext_vector_type(4))) float f4_t;    // 4 f32 MFMA C/D frag

__device__ __forceinline__ unsigned short f2bf(float x) {  // RNE f32->bf16
  unsigned int u = __float_as_uint(x);
  u += 0x7fffu + ((u >> 16) & 1u);
  return (unsigned short)(u >> 16);
}

#define GLDS16(src, dst) __builtin_amdgcn_global_load_lds( \
    (const __attribute__((address_space(1))) void*)(src),  \
    (__attribute__((address_space(3))) void*)(dst), 16, 0, 0)

// ---------------- prep: CSR of (segment -> batch ids) ----------------
__global__ void k_zero(int* counts) {
  int i = blockIdx.x * 256 + threadIdx.x;
  if (i < NSEG) counts[i] = 0;
}

__global__ void k_count(const int* __restrict__ mapper, int* __restrict__ counts) {
  int e = blockIdx.x * 256 + threadIdx.x;
  if (e < EN) atomicAdd(&counts[mapper[e]], 1);
}

__global__ __launch_bounds__(1024) void k_scan(const int* __restrict__ counts,
                                               int* __restrict__ offs,
                                               int* __restrict__ cursor) {
  __shared__ int sd[1024];
  const int t = threadIdx.x;
  int loc[40];
  int sum = 0;
  #pragma unroll
  for (int i = 0; i < 40; ++i) {
    int idx = t * 40 + i;
    int v = (idx < NSEG) ? counts[idx] : 0;
    loc[i] = sum;
    sum += v;
  }
  sd[t] = sum;
  __syncthreads();
  for (int off = 1; off < 1024; off <<= 1) {
    int v = (t >= off) ? sd[t - off] : 0;
    __syncthreads();
    sd[t] += v;
    __syncthreads();
  }
  const int ebase = sd[t] - sum;  // exclusive prefix for this thread's chunk
  #pragma unroll
  for (int i = 0; i < 40; ++i) {
    int idx = t * 40 + i;
    if (idx < NSEG) { int o = ebase + loc[i]; offs[idx] = o; cursor[idx] = o; }
  }
}

__global__ void k_scatter(const int* __restrict__ mapper, const int* __restrict__ batch,
                          int* __restrict__ cursor, int* __restrict__ sorted) {
  int e = blockIdx.x * 256 + threadIdx.x;
  if (e < EN) {
    int s = mapper[e];
    int pos = atomicAdd(&cursor[s], 1);
    sorted[pos] = batch[e];
  }
}

// ---------------- weight prep ----------------
// Wt[n][k] = W[k][n], zero-padded to [Nrows][KD] bf16. W is [780][ldw].
__global__ void k_tpad(const float* __restrict__ W, unsigned short* __restrict__ Wt,
                       int ldw, int nsrc, int total) {
  int idx = blockIdx.x * 256 + threadIdx.x;
  if (idx >= total) return;
  int n = idx / KD, k = idx % KD;
  float v = (n < nsrc && k < 780) ? W[k * ldw + n] : 0.f;
  Wt[idx] = f2bf(v);
}

__global__ void k_padbias(const float* __restrict__ b1, const float* __restrict__ b2,
                          float* __restrict__ p1, float* __restrict__ p2) {
  int i = blockIdx.x * 256 + threadIdx.x;
  if (i < KD) p1[i] = (i < 780) ? b1[i] : 0.f;
  else if (i < 2 * KD) { int c = i - KD; p2[c] = (c < 780) ? b2[c] : 0.f; }
}

// flatW0[j][c] = sum_k flat[j][k] * W0[12+k][c], j<128, c<780 (0 for 780<=c<800)
// flat[j][t*64+f] = mixer_x[j%4][t][j/4][f]
// Split-K f32: grid (13 c-tiles x 16 j-tiles), block 256 = 64 c-lanes x 4 k-splits.
// Each k-iter: 1 coalesced W0 load feeds 8 independent FMAs (ILP over j).
__global__ __launch_bounds__(256) void k_flatW0(const float* __restrict__ mixer,
                                                const float* __restrict__ W0,
                                                float* __restrict__ fW0) {
  __shared__ float sA[8][768];       // 24 KB: 8 A-rows
  __shared__ float sRed[4][64][9];   // 9.2 KB, pad 9 -> conflict-free
  const int tid = threadIdx.x;
  const int c0 = blockIdx.x * 64, j0 = blockIdx.y * 8;
  for (int i = tid; i < 8 * 768; i += 256) {
    int jj = i / 768;
    int k = i - jj * 768;
    int j = j0 + jj;
    int tt = k >> 6, ff = k & 63;
    sA[jj][k] = mixer[(((j & 3) * TT + tt) * 32 + (j >> 2)) * 64 + ff];
  }
  __syncthreads();
  const int cc = tid & 63, ks = tid >> 6;
  const int c = c0 + cc;
  float acc[8] = {};
  if (c < 780) {
    const float* wp = W0 + (size_t)(12 + ks * 192) * 780 + c;
    #pragma unroll 4
    for (int k = ks * 192; k < ks * 192 + 192; ++k) {
      const float w = *wp; wp += 780;
      #pragma unroll
      for (int jj = 0; jj < 8; ++jj) acc[jj] = fmaf(sA[jj][k], w, acc[jj]);
    }
  }
  #pragma unroll
  for (int jj = 0; jj < 8; ++jj) sRed[ks][cc][jj] = acc[jj];
  __syncthreads();
  for (int o = tid; o < 512; o += 256) {
    const int oc = o & 63, jj = o >> 6;
    const int wc = c0 + oc;
    if (wc < KD) {
      float s = sRed[0][oc][jj] + sRed[1][oc][jj] + sRed[2][oc][jj] + sRed[3][oc][jj];
      fW0[(size_t)(j0 + jj) * KD + wc] = s;  // cols >=780 stayed 0
    }
  }
}

// ---------------- layer 0 (sparse mean of flatW0 rows + passthrough GEMV) ----------------
__global__ __launch_bounds__(256) void k_layer0(
    const float* __restrict__ features, const int* __restrict__ counts,
    const int* __restrict__ offs, const int* __restrict__ sorted,
    const float* __restrict__ fW0, const float* __restrict__ W0,
    const float* __restrict__ b0, unsigned short* __restrict__ h0) {
  __shared__ float sW0[12 * KD];   // passthrough weights, padded
  const int tid = threadIdx.x, lane = tid & 63, wid = tid >> 6;
  for (int tt = 0; tt < 12; ++tt)
    for (int c = tid; c < KD; c += 256)
      sW0[tt * KD + c] = (c < 780) ? W0[tt * 780 + c] : 0.f;
  __syncthreads();

  float bcol[13];
  #pragma unroll
  for (int cc = 0; cc < 13; ++cc) {
    int col = cc * 64 + lane;
    bcol[cc] = (col < 780) ? b0[col] : 0.f;
  }

  for (int i = 0; i < 32; ++i) {
    const int r = blockIdx.x * 128 + wid * 32 + i;
    unsigned short* hr = h0 + (size_t)r * KD;
    if (r < NROWS) {
      const int s = (r % NN) * BG + (r / NN);
      const int cnt = counts[s];
      const int e0 = offs[s];
      float acc[13];
      #pragma unroll
      for (int cc = 0; cc < 13; ++cc) acc[cc] = 0.f;
      for (int e = e0; e < e0 + cnt; ++e) {
        const int j = sorted[e];                    // wave-uniform broadcast load
        const float* fw = fW0 + j * KD;
        #pragma unroll
        for (int cc = 0; cc < 13; ++cc) {
          int col = cc * 64 + lane;
          if (col < KD) acc[cc] += fw[col];
        }
      }
      const float inv = 1.f / (float)(cnt > 0 ? cnt : 1);
      #pragma unroll
      for (int cc = 0; cc < 13; ++cc) acc[cc] *= inv;
      const float* fr = features + (size_t)r * TT;
      #pragma unroll
      for (int t2 = 0; t2 < 12; ++t2) {
        const float ft = fr[t2];
        #pragma unroll
        for (int cc = 0; cc < 13; ++cc) {
          int col = cc * 64 + lane;
          if (col < KD) acc[cc] = fmaf(ft, sW0[t2 * KD + col], acc[cc]);
        }
      }
      #pragma unroll
      for (int cc = 0; cc < 13; ++cc) {
        int col = cc * 64 + lane;
        if (col < KD) hr[col] = f2bf(fmaxf(acc[cc] + bcol[cc], 0.f));
      }
    } else {  // pad rows 40000..40063: clean zeros for the GEMM
      #pragma unroll
      for (int cc = 0; cc < 13; ++cc) {
        int col = cc * 64 + lane;
        if (col < KD) hr[col] = 0;
      }
    }
  }
}

// ---------------- dense layers: C = relu(A @ W + b), bf16 MFMA ----------------
// A [MPAD][KD] bf16, WT [NPW][KD] bf16 (= W transposed, padded), C [MPAD][KD] bf16.
// m97 structure: 128x128 tile, BK=32, 4 waves (2x2), global_load_lds w=16.
// SWAPPED operands: mfma(Wfrag, Afrag, acc) -> lane holds 4 consecutive output
// COLUMNS (packed 8B bf16 stores) at output row = lane&15.
__global__ __launch_bounds__(256) void gemm_relu(
    const unsigned short* __restrict__ A, const unsigned short* __restrict__ WT,
    const float* __restrict__ bias, unsigned short* __restrict__ C) {
  __shared__ unsigned short sA[128 * 32];
  __shared__ unsigned short sB[128 * 32];
  const int tid = threadIdx.x, lane = tid & 63, wid = tid >> 6;
  const int wm = wid >> 1, wn = wid & 1;
  const int row0 = blockIdx.x * 128, n0 = blockIdx.y * 128;
  const char* gA = (const char*)A + (size_t)row0 * (KD * 2);
  const char* gB = (const char*)WT + (size_t)n0 * (KD * 2);
  const int frow = lane & 15, fk = (lane >> 4) * 8;

  f4_t acc[4][4] = {};

  for (int kt = 0; kt < 25; ++kt) {
    const int kb = kt * 64;  // byte offset of 32-element K chunk
    __syncthreads();
    #pragma unroll
    for (int L = 0; L < 2; ++L) {
      const int segb = L * 256 + wid * 64;
      const int seg = segb + lane;
      const size_t go = (size_t)(seg >> 2) * (KD * 2) + kb + (seg & 3) * 16;
      GLDS16(gA + go, (char*)sA + segb * 16);
      GLDS16(gB + go, (char*)sB + segb * 16);
    }
    __syncthreads();
    bf8_t af[4], bf[4];
    #pragma unroll
    for (int mi = 0; mi < 4; ++mi)
      af[mi] = *(const bf8_t*)(sA + (wm * 64 + mi * 16 + frow) * 32 + fk);
    #pragma unroll
    for (int ni = 0; ni < 4; ++ni)
      bf[ni] = *(const bf8_t*)(sB + (wn * 64 + ni * 16 + frow) * 32 + fk);
    #pragma unroll
    for (int mi = 0; mi < 4; ++mi)
      #pragma unroll
      for (int ni = 0; ni < 4; ++ni)
        acc[mi][ni] = __builtin_amdgcn_mfma_f32_16x16x32_bf16(bf[ni], af[mi], acc[mi][ni], 0, 0, 0);
  }

  const int cq = (lane >> 4) * 4;
  #pragma unroll
  for (int mi = 0; mi < 4; ++mi) {
    const int r = row0 + wm * 64 + mi * 16 + frow;
    unsigned short* crow = C + (size_t)r * KD;
    #pragma unroll
    for (int ni = 0; ni < 4; ++ni) {
      const int c = n0 + wn * 64 + ni * 16 + cq;
      if (c < KD) {  // wave-uniform per fragment
        f4_t v = acc[mi][ni];
        const f4_t bb = *(const f4_t*)(bias + c);
        float v0 = fmaxf(v[0] + bb[0], 0.f);
        float v1 = fmaxf(v[1] + bb[1], 0.f);
        float v2 = fmaxf(v[2] + bb[2], 0.f);
        float v3 = fmaxf(v[3] + bb[3], 0.f);
        uint2 pk;
        pk.x = (unsigned int)f2bf(v0) | ((unsigned int)f2bf(v1) << 16);
        pk.y = (unsigned int)f2bf(v2) | ((unsigned int)f2bf(v3) << 16);
        *(uint2*)(crow + c) = pk;
      }
    }
  }
}

// ---------------- final layer: out = A @ W3 + b3 (N=16 padded, write 12 cols f32) ----------
__global__ __launch_bounds__(256) void gemm_out(
    const unsigned short* __restrict__ A, const unsigned short* __restrict__ WT3,
    const float* __restrict__ b3, float* __restrict__ out) {
  __shared__ unsigned short sA[128 * 32];
  __shared__ unsigned short sB[16 * 32];
  const int tid = threadIdx.x, lane = tid & 63, wid = tid >> 6;
  const int row0 = blockIdx.x * 128;
  const char* gA = (const char*)A + (size_t)row0 * (KD * 2);
  const char* gB = (const char*)WT3;
  const int frow = lane & 15, fk = (lane >> 4) * 8;

  f4_t acc[2] = {};

  for (int kt = 0; kt < 25; ++kt) {
    const int kb = kt * 64;
    __syncthreads();
    #pragma unroll
    for (int L = 0; L < 2; ++L) {
      const int segb = L * 256 + wid * 64;
      const int seg = segb + lane;
      GLDS16(gA + (size_t)(seg >> 2) * (KD * 2) + kb + (seg & 3) * 16, (char*)sA + segb * 16);
    }
    if (wid == 0) {
      const int seg = lane;  // 16 rows x 32 K = 64 x 16B
      GLDS16(gB + (size_t)(seg >> 2) * (KD * 2) + kb + (seg & 3) * 16, (char*)sB);
    }
    __syncthreads();
    const bf8_t bf = *(const bf8_t*)(sB + frow * 32 + fk);
    #pragma unroll
    for (int mi = 0; mi < 2; ++mi) {
      const bf8_t af = *(const bf8_t*)(sA + (wid * 32 + mi * 16 + frow) * 32 + fk);
      acc[mi] = __builtin_amdgcn_mfma_f32_16x16x32_bf16(bf, af, acc[mi], 0, 0, 0);
    }
  }

  const int cg = (lane >> 4) * 4;
  #pragma unroll
  for (int mi = 0; mi < 2; ++mi) {
    const int r = row0 + wid * 32 + mi * 16 + frow;
    if (r < NROWS && cg < 12) {
      f4_t v = acc[mi];
      const f4_t bb = *(const f4_t*)(b3 + cg);  // cg in {0,4,8}: reads b3[0..11]
      v += bb;
      *(f4_t*)(out + (size_t)r * 12 + cg) = v;
    }
  }
}

// ---------------- host ----------------
extern "C" void kernel_launch(void* const* d_in, const int* in_sizes, int n_in,
                              void* d_out, int out_size, void* d_ws, size_t ws_size,
                              hipStream_t stream) {
  const float* mixer    = (const float*)d_in[0];
  const float* features = (const float*)d_in[1];
  const int*   sg_batch = (const int*)d_in[2];
  const int*   sg_map   = (const int*)d_in[3];
  const float* W0 = (const float*)d_in[4];  const float* b0 = (const float*)d_in[5];
  const float* W1 = (const float*)d_in[6];  const float* b1 = (const float*)d_in[7];
  const float* W2 = (const float*)d_in[8];  const float* b2 = (const float*)d_in[9];
  const float* W3 = (const float*)d_in[10]; const float* b3 = (const float*)d_in[11];
  float* out = (float*)d_out;

  char* wsp = (char*)d_ws;
  auto alloc = [&](size_t bytes) { char* p = wsp; wsp += (bytes + 255) & ~(size_t)255; return p; };
  unsigned short* h0  = (unsigned short*)alloc((size_t)MPAD * KD * 2);   // 64.1 MB
  unsigned short* h1  = (unsigned short*)alloc((size_t)MPAD * KD * 2);   // 64.1 MB
  unsigned short* Wt1 = (unsigned short*)alloc((size_t)NPW * KD * 2);
  unsigned short* Wt2 = (unsigned short*)alloc((size_t)NPW * KD * 2);
  unsigned short* Wt3 = (unsigned short*)alloc((size_t)16 * KD * 2);
  float* bp1   = (float*)alloc(KD * 4);
  float* bp2   = (float*)alloc(KD * 4);
  float* fW0   = (float*)alloc((size_t)128 * KD * 4);
  int* counts  = (int*)alloc(NSEG * 4);
  int* offs    = (int*)alloc(NSEG * 4);
  int* cursor  = (int*)alloc(NSEG * 4);
  int* sorted  = (int*)alloc(EN * 4);

  // CSR build
  k_zero<<<(NSEG + 255) / 256, 256, 0, stream>>>(counts);
  k_count<<<(EN + 255) / 256, 256, 0, stream>>>(sg_map, counts);
  k_scan<<<1, 1024, 0, stream>>>(counts, offs, cursor);
  k_scatter<<<(EN + 255) / 256, 256, 0, stream>>>(sg_map, sg_batch, cursor, sorted);

  // weight prep
  k_tpad<<<(NPW * KD + 255) / 256, 256, 0, stream>>>(W1, Wt1, 780, 780, NPW * KD);
  k_tpad<<<(NPW * KD + 255) / 256, 256, 0, stream>>>(W2, Wt2, 780, 780, NPW * KD);
  k_tpad<<<(16 * KD + 255) / 256, 256, 0, stream>>>(W3, Wt3, 12, 12, 16 * KD);
  k_padbias<<<7, 256, 0, stream>>>(b1, b2, bp1, bp2);
  k_flatW0<<<dim3(13, 16), 256, 0, stream>>>(mixer, W0, fW0);

  // layer 0 (sparse) -> h0
  k_layer0<<<MPAD / 128, 256, 0, stream>>>(features, counts, offs, sorted, fW0, W0, b0, h0);

  // layers 1,2 (dense bf16 MFMA) -> h1 -> h0
  gemm_relu<<<dim3(MPAD / 128, NPW / 128), 256, 0, stream>>>(h0, Wt1, bp1, h1);
  gemm_relu<<<dim3(MPAD / 128, NPW / 128), 256, 0, stream>>>(h1, Wt2, bp2, h0);

  // layer 3 -> out
  gemm_out<<<MPAD / 128, 256, 0, stream>>>(h0, Wt3, b3, out);
}

// Round 4
// 522.112 us; speedup vs baseline: 1.5274x; 1.1202x over previous
//
#include <hip/hip_runtime.h>

// Problem constants (fixed by setup_inputs)
#define BG    4        // num_graphs
#define TT    12       // timesteps
#define NN    10000    // nodes per graph
#define EN    200000   // membership entries
#define NSEG  40000    // n*B segments
#define NROWS 40000    // B*n output rows
#define MPAD  40064    // 313*128
#define KD    800      // padded in_dim (780 -> 800 = 25*32)
#define NPW   896      // padded N for weight tiles (7*128)

typedef __attribute__((ext_vector_type(8))) short bf8_t;   // 8 bf16 (4 VGPR) MFMA A/B frag
typedef __attribute__((ext_vector_type(4))) float f4_t;    // 4 f32 MFMA C/D frag

__device__ __forceinline__ unsigned short f2bf(float x) {  // RNE f32->bf16
  unsigned int u = __float_as_uint(x);
  u += 0x7fffu + ((u >> 16) & 1u);
  return (unsigned short)(u >> 16);
}

#define GLDS16(src, dst) __builtin_amdgcn_global_load_lds( \
    (const __attribute__((address_space(1))) void*)(src),  \
    (__attribute__((address_space(3))) void*)(dst), 16, 0, 0)

// ---------------- prep: CSR of (segment -> batch ids) ----------------
__global__ void k_zero(int* counts) {
  int i = blockIdx.x * 256 + threadIdx.x;
  if (i < NSEG) counts[i] = 0;
}

__global__ void k_count(const int* __restrict__ mapper, int* __restrict__ counts) {
  int e = blockIdx.x * 256 + threadIdx.x;
  if (e < EN) atomicAdd(&counts[mapper[e]], 1);
}

__global__ __launch_bounds__(1024) void k_scan(const int* __restrict__ counts,
                                               int* __restrict__ offs,
                                               int* __restrict__ cursor) {
  __shared__ int sd[1024];
  const int t = threadIdx.x;
  int loc[40];
  int sum = 0;
  #pragma unroll
  for (int i = 0; i < 40; ++i) {
    int idx = t * 40 + i;
    int v = (idx < NSEG) ? counts[idx] : 0;
    loc[i] = sum;
    sum += v;
  }
  sd[t] = sum;
  __syncthreads();
  for (int off = 1; off < 1024; off <<= 1) {
    int v = (t >= off) ? sd[t - off] : 0;
    __syncthreads();
    sd[t] += v;
    __syncthreads();
  }
  const int ebase = sd[t] - sum;  // exclusive prefix for this thread's chunk
  #pragma unroll
  for (int i = 0; i < 40; ++i) {
    int idx = t * 40 + i;
    if (idx < NSEG) { int o = ebase + loc[i]; offs[idx] = o; cursor[idx] = o; }
  }
}

__global__ void k_scatter(const int* __restrict__ mapper, const int* __restrict__ batch,
                          int* __restrict__ cursor, int* __restrict__ sorted) {
  int e = blockIdx.x * 256 + threadIdx.x;
  if (e < EN) {
    int s = mapper[e];
    int pos = atomicAdd(&cursor[s], 1);
    sorted[pos] = batch[e];
  }
}

// ---------------- weight prep ----------------
// Wt[n][k] = W[k][n], zero-padded to [Nrows][KD] bf16. W is [780][ldw].
__global__ void k_tpad(const float* __restrict__ W, unsigned short* __restrict__ Wt,
                       int ldw, int nsrc, int total) {
  int idx = blockIdx.x * 256 + threadIdx.x;
  if (idx >= total) return;
  int n = idx / KD, k = idx % KD;
  float v = (n < nsrc && k < 780) ? W[k * ldw + n] : 0.f;
  Wt[idx] = f2bf(v);
}

__global__ void k_padbias(const float* __restrict__ b1, const float* __restrict__ b2,
                          float* __restrict__ p1, float* __restrict__ p2) {
  int i = blockIdx.x * 256 + threadIdx.x;
  if (i < KD) p1[i] = (i < 780) ? b1[i] : 0.f;
  else if (i < 2 * KD) { int c = i - KD; p2[c] = (c < 780) ? b2[c] : 0.f; }
}

// flatW0[j][c] = sum_k flat[j][k] * W0[12+k][c], j<128, c<780 (0 for 780<=c<800)
// flat[j][t*64+f] = mixer_x[j%4][t][j/4][f]
// Split-K f32: grid (13 c-tiles x 16 j-tiles), block 256 = 64 c-lanes x 4 k-splits.
// Each k-iter: 1 coalesced W0 load feeds 8 independent FMAs (ILP over j).
__global__ __launch_bounds__(256) void k_flatW0(const float* __restrict__ mixer,
                                                const float* __restrict__ W0,
                                                float* __restrict__ fW0) {
  __shared__ float sA[8][768];       // 24 KB: 8 A-rows
  __shared__ float sRed[4][64][9];   // 9.2 KB, pad 9 -> conflict-free
  const int tid = threadIdx.x;
  const int c0 = blockIdx.x * 64, j0 = blockIdx.y * 8;
  for (int i = tid; i < 8 * 768; i += 256) {
    int jj = i / 768;
    int k = i - jj * 768;
    int j = j0 + jj;
    int tt = k >> 6, ff = k & 63;
    sA[jj][k] = mixer[(((j & 3) * TT + tt) * 32 + (j >> 2)) * 64 + ff];
  }
  __syncthreads();
  const int cc = tid & 63, ks = tid >> 6;
  const int c = c0 + cc;
  float acc[8] = {};
  if (c < 780) {
    const float* wp = W0 + (size_t)(12 + ks * 192) * 780 + c;
    #pragma unroll 4
    for (int k = ks * 192; k < ks * 192 + 192; ++k) {
      const float w = *wp; wp += 780;
      #pragma unroll
      for (int jj = 0; jj < 8; ++jj) acc[jj] = fmaf(sA[jj][k], w, acc[jj]);
    }
  }
  #pragma unroll
  for (int jj = 0; jj < 8; ++jj) sRed[ks][cc][jj] = acc[jj];
  __syncthreads();
  for (int o = tid; o < 512; o += 256) {
    const int oc = o & 63, jj = o >> 6;
    const int wc = c0 + oc;
    if (wc < KD) {
      float s = sRed[0][oc][jj] + sRed[1][oc][jj] + sRed[2][oc][jj] + sRed[3][oc][jj];
      fW0[(size_t)(j0 + jj) * KD + wc] = s;  // cols >=780 stayed 0
    }
  }
}

// ---------------- layer 0 (sparse mean of flatW0 rows + passthrough GEMV) ----------------
// Occupancy fix (R3): 32 rows/block (grid 1252), 8 rows per wave. LDS 38.4KB ->
// 4 blocks/CU = 16 waves/CU (~50%) vs prior 313-block launch (~12%).
__global__ __launch_bounds__(256) void k_layer0(
    const float* __restrict__ features, const int* __restrict__ counts,
    const int* __restrict__ offs, const int* __restrict__ sorted,
    const float* __restrict__ fW0, const float* __restrict__ W0,
    const float* __restrict__ b0, unsigned short* __restrict__ h0) {
  __shared__ float sW0[12 * KD];   // passthrough weights, padded
  const int tid = threadIdx.x, lane = tid & 63, wid = tid >> 6;
  for (int i = tid; i < 12 * KD; i += 256) {
    const int tt2 = i / KD, c = i - tt2 * KD;
    sW0[i] = (c < 780) ? W0[tt2 * 780 + c] : 0.f;
  }
  __syncthreads();

  float bcol[13];
  #pragma unroll
  for (int cc = 0; cc < 13; ++cc) {
    int col = cc * 64 + lane;
    bcol[cc] = (col < 780) ? b0[col] : 0.f;
  }

  for (int i = 0; i < 8; ++i) {
    const int r = blockIdx.x * 32 + wid * 8 + i;
    unsigned short* hr = h0 + (size_t)r * KD;
    if (r < NROWS) {
      const int s = (r % NN) * BG + (r / NN);
      const int cnt = counts[s];
      const int e0 = offs[s];
      float acc[13];
      #pragma unroll
      for (int cc = 0; cc < 13; ++cc) acc[cc] = 0.f;
      for (int e = e0; e < e0 + cnt; ++e) {
        const int j = sorted[e];                    // wave-uniform broadcast load
        const float* fw = fW0 + j * KD;
        #pragma unroll
        for (int cc = 0; cc < 13; ++cc) {
          int col = cc * 64 + lane;
          if (col < KD) acc[cc] += fw[col];
        }
      }
      const float inv = 1.f / (float)(cnt > 0 ? cnt : 1);
      #pragma unroll
      for (int cc = 0; cc < 13; ++cc) acc[cc] *= inv;
      const float* fr = features + (size_t)r * TT;
      #pragma unroll
      for (int t2 = 0; t2 < 12; ++t2) {
        const float ft = fr[t2];
        #pragma unroll
        for (int cc = 0; cc < 13; ++cc) {
          int col = cc * 64 + lane;
          if (col < KD) acc[cc] = fmaf(ft, sW0[t2 * KD + col], acc[cc]);
        }
      }
      #pragma unroll
      for (int cc = 0; cc < 13; ++cc) {
        int col = cc * 64 + lane;
        if (col < KD) hr[col] = f2bf(fmaxf(acc[cc] + bcol[cc], 0.f));
      }
    } else {  // pad rows 40000..40063: clean zeros for the GEMM
      #pragma unroll
      for (int cc = 0; cc < 13; ++cc) {
        int col = cc * 64 + lane;
        if (col < KD) hr[col] = 0;
      }
    }
  }
}

// ---------------- dense layers: C = relu(A @ W + b), bf16 MFMA ----------------
// A [MPAD][KD] bf16, WT [NPW][KD] bf16 (= W transposed, padded), C [MPAD][KD] bf16.
// m97 structure: 128x128 tile, BK=32, 4 waves (2x2), global_load_lds w=16.
// SWAPPED operands: mfma(Wfrag, Afrag, acc) -> lane holds 4 consecutive output
// COLUMNS (packed 8B bf16 stores) at output row = lane&15.
__global__ __launch_bounds__(256) void gemm_relu(
    const unsigned short* __restrict__ A, const unsigned short* __restrict__ WT,
    const float* __restrict__ bias, unsigned short* __restrict__ C) {
  __shared__ unsigned short sA[128 * 32];
  __shared__ unsigned short sB[128 * 32];
  const int tid = threadIdx.x, lane = tid & 63, wid = tid >> 6;
  const int wm = wid >> 1, wn = wid & 1;
  const int row0 = blockIdx.x * 128, n0 = blockIdx.y * 128;
  const char* gA = (const char*)A + (size_t)row0 * (KD * 2);
  const char* gB = (const char*)WT + (size_t)n0 * (KD * 2);
  const int frow = lane & 15, fk = (lane >> 4) * 8;

  f4_t acc[4][4] = {};

  for (int kt = 0; kt < 25; ++kt) {
    const int kb = kt * 64;  // byte offset of 32-element K chunk
    __syncthreads();
    #pragma unroll
    for (int L = 0; L < 2; ++L) {
      const int segb = L * 256 + wid * 64;
      const int seg = segb + lane;
      const size_t go = (size_t)(seg >> 2) * (KD * 2) + kb + (seg & 3) * 16;
      GLDS16(gA + go, (char*)sA + segb * 16);
      GLDS16(gB + go, (char*)sB + segb * 16);
    }
    __syncthreads();
    bf8_t af[4], bf[4];
    #pragma unroll
    for (int mi = 0; mi < 4; ++mi)
      af[mi] = *(const bf8_t*)(sA + (wm * 64 + mi * 16 + frow) * 32 + fk);
    #pragma unroll
    for (int ni = 0; ni < 4; ++ni)
      bf[ni] = *(const bf8_t*)(sB + (wn * 64 + ni * 16 + frow) * 32 + fk);
    #pragma unroll
    for (int mi = 0; mi < 4; ++mi)
      #pragma unroll
      for (int ni = 0; ni < 4; ++ni)
        acc[mi][ni] = __builtin_amdgcn_mfma_f32_16x16x32_bf16(bf[ni], af[mi], acc[mi][ni], 0, 0, 0);
  }

  const int cq = (lane >> 4) * 4;
  #pragma unroll
  for (int mi = 0; mi < 4; ++mi) {
    const int r = row0 + wm * 64 + mi * 16 + frow;
    unsigned short* crow = C + (size_t)r * KD;
    #pragma unroll
    for (int ni = 0; ni < 4; ++ni) {
      const int c = n0 + wn * 64 + ni * 16 + cq;
      if (c < KD) {  // wave-uniform per fragment
        f4_t v = acc[mi][ni];
        const f4_t bb = *(const f4_t*)(bias + c);
        float v0 = fmaxf(v[0] + bb[0], 0.f);
        float v1 = fmaxf(v[1] + bb[1], 0.f);
        float v2 = fmaxf(v[2] + bb[2], 0.f);
        float v3 = fmaxf(v[3] + bb[3], 0.f);
        uint2 pk;
        pk.x = (unsigned int)f2bf(v0) | ((unsigned int)f2bf(v1) << 16);
        pk.y = (unsigned int)f2bf(v2) | ((unsigned int)f2bf(v3) << 16);
        *(uint2*)(crow + c) = pk;
      }
    }
  }
}

// ---------------- final layer: out = A @ W3 + b3 (N=16 padded, write 12 cols f32) ----------
__global__ __launch_bounds__(256) void gemm_out(
    const unsigned short* __restrict__ A, const unsigned short* __restrict__ WT3,
    const float* __restrict__ b3, float* __restrict__ out) {
  __shared__ unsigned short sA[128 * 32];
  __shared__ unsigned short sB[16 * 32];
  const int tid = threadIdx.x, lane = tid & 63, wid = tid >> 6;
  const int row0 = blockIdx.x * 128;
  const char* gA = (const char*)A + (size_t)row0 * (KD * 2);
  const char* gB = (const char*)WT3;
  const int frow = lane & 15, fk = (lane >> 4) * 8;

  f4_t acc[2] = {};

  for (int kt = 0; kt < 25; ++kt) {
    const int kb = kt * 64;
    __syncthreads();
    #pragma unroll
    for (int L = 0; L < 2; ++L) {
      const int segb = L * 256 + wid * 64;
      const int seg = segb + lane;
      GLDS16(gA + (size_t)(seg >> 2) * (KD * 2) + kb + (seg & 3) * 16, (char*)sA + segb * 16);
    }
    if (wid == 0) {
      const int seg = lane;  // 16 rows x 32 K = 64 x 16B
      GLDS16(gB + (size_t)(seg >> 2) * (KD * 2) + kb + (seg & 3) * 16, (char*)sB);
    }
    __syncthreads();
    const bf8_t bf = *(const bf8_t*)(sB + frow * 32 + fk);
    #pragma unroll
    for (int mi = 0; mi < 2; ++mi) {
      const bf8_t af = *(const bf8_t*)(sA + (wid * 32 + mi * 16 + frow) * 32 + fk);
      acc[mi] = __builtin_amdgcn_mfma_f32_16x16x32_bf16(bf, af, acc[mi], 0, 0, 0);
    }
  }

  const int cg = (lane >> 4) * 4;
  #pragma unroll
  for (int mi = 0; mi < 2; ++mi) {
    const int r = row0 + wid * 32 + mi * 16 + frow;
    if (r < NROWS && cg < 12) {
      f4_t v = acc[mi];
      const f4_t bb = *(const f4_t*)(b3 + cg);  // cg in {0,4,8}: reads b3[0..11]
      v += bb;
      *(f4_t*)(out + (size_t)r * 12 + cg) = v;
    }
  }
}

// ---------------- host ----------------
extern "C" void kernel_launch(void* const* d_in, const int* in_sizes, int n_in,
                              void* d_out, int out_size, void* d_ws, size_t ws_size,
                              hipStream_t stream) {
  const float* mixer    = (const float*)d_in[0];
  const float* features = (const float*)d_in[1];
  const int*   sg_batch = (const int*)d_in[2];
  const int*   sg_map   = (const int*)d_in[3];
  const float* W0 = (const float*)d_in[4];  const float* b0 = (const float*)d_in[5];
  const float* W1 = (const float*)d_in[6];  const float* b1 = (const float*)d_in[7];
  const float* W2 = (const float*)d_in[8];  const float* b2 = (const float*)d_in[9];
  const float* W3 = (const float*)d_in[10]; const float* b3 = (const float*)d_in[11];
  float* out = (float*)d_out;

  char* wsp = (char*)d_ws;
  auto alloc = [&](size_t bytes) { char* p = wsp; wsp += (bytes + 255) & ~(size_t)255; return p; };
  unsigned short* h0  = (unsigned short*)alloc((size_t)MPAD * KD * 2);   // 64.1 MB
  unsigned short* h1  = (unsigned short*)alloc((size_t)MPAD * KD * 2);   // 64.1 MB
  unsigned short* Wt1 = (unsigned short*)alloc((size_t)NPW * KD * 2);
  unsigned short* Wt2 = (unsigned short*)alloc((size_t)NPW * KD * 2);
  unsigned short* Wt3 = (unsigned short*)alloc((size_t)16 * KD * 2);
  float* bp1   = (float*)alloc(KD * 4);
  float* bp2   = (float*)alloc(KD * 4);
  float* fW0   = (float*)alloc((size_t)128 * KD * 4);
  int* counts  = (int*)alloc(NSEG * 4);
  int* offs    = (int*)alloc(NSEG * 4);
  int* cursor  = (int*)alloc(NSEG * 4);
  int* sorted  = (int*)alloc(EN * 4);

  // CSR build
  k_zero<<<(NSEG + 255) / 256, 256, 0, stream>>>(counts);
  k_count<<<(EN + 255) / 256, 256, 0, stream>>>(sg_map, counts);
  k_scan<<<1, 1024, 0, stream>>>(counts, offs, cursor);
  k_scatter<<<(EN + 255) / 256, 256, 0, stream>>>(sg_map, sg_batch, cursor, sorted);

  // weight prep
  k_tpad<<<(NPW * KD + 255) / 256, 256, 0, stream>>>(W1, Wt1, 780, 780, NPW * KD);
  k_tpad<<<(NPW * KD + 255) / 256, 256, 0, stream>>>(W2, Wt2, 780, 780, NPW * KD);
  k_tpad<<<(16 * KD + 255) / 256, 256, 0, stream>>>(W3, Wt3, 12, 12, 16 * KD);
  k_padbias<<<7, 256, 0, stream>>>(b1, b2, bp1, bp2);
  k_flatW0<<<dim3(13, 16), 256, 0, stream>>>(mixer, W0, fW0);

  // layer 0 (sparse) -> h0
  k_layer0<<<MPAD / 32, 256, 0, stream>>>(features, counts, offs, sorted, fW0, W0, b0, h0);

  // layers 1,2 (dense bf16 MFMA) -> h1 -> h0
  gemm_relu<<<dim3(MPAD / 128, NPW / 128), 256, 0, stream>>>(h0, Wt1, bp1, h1);
  gemm_relu<<<dim3(MPAD / 128, NPW / 128), 256, 0, stream>>>(h1, Wt2, bp2, h0);

  // layer 3 -> out
  gemm_out<<<MPAD / 128, 256, 0, stream>>>(h0, Wt3, b3, out);
}

// Round 6
// 406.695 us; speedup vs baseline: 1.9608x; 1.2838x over previous
//
#include <hip/hip_runtime.h>

// Problem constants (fixed by setup_inputs)
#define BG    4        // num_graphs
#define TT    12       // timesteps
#define NN    10000    // nodes per graph
#define EN    200000   // membership entries
#define NSEG  40000    // n*B segments
#define NROWS 40000    // B*n output rows
#define MPAD  40064    // 313*128
#define KD    800      // padded in_dim (780 -> 800 = 25*32)
#define KA0   160      // padded K for layer0 GEMM: 12 features + 128 Cf + 20 zero
#define NPW   896      // padded N for weight tiles (7*128)

typedef __attribute__((ext_vector_type(8))) short bf8_t;   // 8 bf16 (4 VGPR) MFMA A/B frag
typedef __attribute__((ext_vector_type(4))) float f4_t;    // 4 f32 MFMA C/D frag

__device__ __forceinline__ unsigned short f2bf(float x) {  // RNE f32->bf16
  unsigned int u = __float_as_uint(x);
  u += 0x7fffu + ((u >> 16) & 1u);
  return (unsigned short)(u >> 16);
}

#define GLDS16(src, dst) __builtin_amdgcn_global_load_lds( \
    (const __attribute__((address_space(1))) void*)(src),  \
    (__attribute__((address_space(3))) void*)(dst), 16, 0, 0)

// ---------------- prep ----------------
__global__ void k_zero(int* counts) {
  int i = blockIdx.x * 256 + threadIdx.x;
  if (i < NSEG) counts[i] = 0;
}

__global__ void k_count(const int* __restrict__ mapper, int* __restrict__ counts) {
  int e = blockIdx.x * 256 + threadIdx.x;
  if (e < EN) atomicAdd(&counts[mapper[e]], 1);
}

__global__ void k_zerof(float* __restrict__ p, int n) {
  int i = blockIdx.x * 256 + threadIdx.x;
  if (i < n) p[i] = 0.f;
}

// Cf scatter: entry e contributes 1 to Cff[r][batch[e]], r = output row of segment mapper[e]
__global__ void k_scatterCf(const int* __restrict__ mapper, const int* __restrict__ batch,
                            float* __restrict__ Cff) {
  int e = blockIdx.x * 256 + threadIdx.x;
  if (e < EN) {
    const int s = mapper[e];
    const int r = (s % BG) * NN + s / BG;   // inverse of s = (r%NN)*BG + r/NN
    atomicAdd(&Cff[(size_t)r * 128 + batch[e]], 1.0f);
  }
}

// A = [features(12) | Cf(128) | 0(20)] as bf16, [MPAD][KA0]
__global__ void k_buildA(const float* __restrict__ features, const int* __restrict__ counts,
                         const float* __restrict__ Cff, unsigned short* __restrict__ A) {
  int idx = blockIdx.x * 256 + threadIdx.x;
  if (idx >= MPAD * KA0) return;
  const int r = idx / KA0, c = idx - r * KA0;
  float v = 0.f;
  if (r < NROWS) {
    if (c < 12) {
      v = features[(size_t)r * TT + c];
    } else if (c < 140) {
      const int s = (r % NN) * BG + (r / NN);
      const int cnt = counts[s];
      const float inv = 1.f / (float)(cnt > 0 ? cnt : 1);
      v = Cff[(size_t)r * 128 + (c - 12)] * inv;
    }
  }
  A[idx] = f2bf(v);
}

// B^T for layer0 GEMM: WTB[n][k] = k<12 ? W0[k][n] : k<140 ? fW0[k-12][n] : 0; [NPW][KA0]
__global__ void k_buildB(const float* __restrict__ W0, const float* __restrict__ fW0,
                         unsigned short* __restrict__ WTB) {
  int idx = blockIdx.x * 256 + threadIdx.x;
  if (idx >= NPW * KA0) return;
  const int n = idx / KA0, k = idx - n * KA0;
  float v = 0.f;
  if (n < 780) {
    if (k < 12) v = W0[(size_t)k * 780 + n];
    else if (k < 140) v = fW0[(size_t)(k - 12) * KD + n];
  }
  WTB[idx] = f2bf(v);
}

// Wt[n][k] = W[k][n], zero-padded to [Nrows][KD] bf16. W is [780][ldw].
__global__ void k_tpad(const float* __restrict__ W, unsigned short* __restrict__ Wt,
                       int ldw, int nsrc, int total) {
  int idx = blockIdx.x * 256 + threadIdx.x;
  if (idx >= total) return;
  int n = idx / KD, k = idx % KD;
  float v = (n < nsrc && k < 780) ? W[k * ldw + n] : 0.f;
  Wt[idx] = f2bf(v);
}

// pad b0,b1,b2 -> bp0,bp1,bp2 (KD wide, zeros past 780)
__global__ void k_padbias3(const float* __restrict__ b0, const float* __restrict__ b1,
                           const float* __restrict__ b2, float* __restrict__ p0,
                           float* __restrict__ p1, float* __restrict__ p2) {
  int i = blockIdx.x * 256 + threadIdx.x;
  if (i >= 3 * KD) return;
  const int which = i / KD, c = i - which * KD;
  const float* src = which == 0 ? b0 : (which == 1 ? b1 : b2);
  float* dst = which == 0 ? p0 : (which == 1 ? p1 : p2);
  dst[c] = (c < 780) ? src[c] : 0.f;
}

// flatW0[j][c] = sum_k flat[j][k] * W0[12+k][c], j<128, c<780 (0 for 780<=c<800)
// flat[j][t*64+f] = mixer_x[j%4][t][j/4][f]
// Split-K f32: grid (13 c-tiles x 16 j-tiles), block 256 = 64 c-lanes x 4 k-splits.
__global__ __launch_bounds__(256) void k_flatW0(const float* __restrict__ mixer,
                                                const float* __restrict__ W0,
                                                float* __restrict__ fW0) {
  __shared__ float sA[8][768];       // 24 KB: 8 A-rows
  __shared__ float sRed[4][64][9];   // 9.2 KB, pad 9 -> conflict-free
  const int tid = threadIdx.x;
  const int c0 = blockIdx.x * 64, j0 = blockIdx.y * 8;
  for (int i = tid; i < 8 * 768; i += 256) {
    int jj = i / 768;
    int k = i - jj * 768;
    int j = j0 + jj;
    int tt = k >> 6, ff = k & 63;
    sA[jj][k] = mixer[(((j & 3) * TT + tt) * 32 + (j >> 2)) * 64 + ff];
  }
  __syncthreads();
  const int cc = tid & 63, ks = tid >> 6;
  const int c = c0 + cc;
  float acc[8] = {};
  if (c < 780) {
    const float* wp = W0 + (size_t)(12 + ks * 192) * 780 + c;
    #pragma unroll 4
    for (int k = ks * 192; k < ks * 192 + 192; ++k) {
      const float w = *wp; wp += 780;
      #pragma unroll
      for (int jj = 0; jj < 8; ++jj) acc[jj] = fmaf(sA[jj][k], w, acc[jj]);
    }
  }
  #pragma unroll
  for (int jj = 0; jj < 8; ++jj) sRed[ks][cc][jj] = acc[jj];
  __syncthreads();
  for (int o = tid; o < 512; o += 256) {
    const int oc = o & 63, jj = o >> 6;
    const int wc = c0 + oc;
    if (wc < KD) {
      float s = sRed[0][oc][jj] + sRed[1][oc][jj] + sRed[2][oc][jj] + sRed[3][oc][jj];
      fW0[(size_t)(j0 + jj) * KD + wc] = s;  // cols >=780 stayed 0
    }
  }
}

// ---------------- dense layers: C = relu(A @ W + b), bf16 MFMA ----------------
// A [MPAD][KA] bf16, WT [*][KA] bf16, C [MPAD][KD] bf16 (output stride always KD).
// m97 structure: 128x128 tile, BK=32, 4 waves (2x2), global_load_lds w=16.
// SWAPPED operands: mfma(Wfrag, Afrag, acc) -> lane holds 4 consecutive output
// COLUMNS (packed 8B bf16 stores) at output row = lane&15.
template<int KA>
__global__ __launch_bounds__(256) void gemm_relu(
    const unsigned short* __restrict__ A, const unsigned short* __restrict__ WT,
    const float* __restrict__ bias, unsigned short* __restrict__ C) {
  __shared__ unsigned short sA[128 * 32];
  __shared__ unsigned short sB[128 * 32];
  const int tid = threadIdx.x, lane = tid & 63, wid = tid >> 6;
  const int wm = wid >> 1, wn = wid & 1;
  const int row0 = blockIdx.x * 128, n0 = blockIdx.y * 128;
  const char* gA = (const char*)A + (size_t)row0 * (KA * 2);
  const char* gB = (const char*)WT + (size_t)n0 * (KA * 2);
  const int frow = lane & 15, fk = (lane >> 4) * 8;

  f4_t acc[4][4] = {};

  for (int kt = 0; kt < KA / 32; ++kt) {
    const int kb = kt * 64;  // byte offset of 32-element K chunk
    __syncthreads();
    #pragma unroll
    for (int L = 0; L < 2; ++L) {
      const int segb = L * 256 + wid * 64;
      const int seg = segb + lane;
      const size_t go = (size_t)(seg >> 2) * (KA * 2) + kb + (seg & 3) * 16;
      GLDS16(gA + go, (char*)sA + segb * 16);
      GLDS16(gB + go, (char*)sB + segb * 16);
    }
    __syncthreads();
    bf8_t af[4], bf[4];
    #pragma unroll
    for (int mi = 0; mi < 4; ++mi)
      af[mi] = *(const bf8_t*)(sA + (wm * 64 + mi * 16 + frow) * 32 + fk);
    #pragma unroll
    for (int ni = 0; ni < 4; ++ni)
      bf[ni] = *(const bf8_t*)(sB + (wn * 64 + ni * 16 + frow) * 32 + fk);
    #pragma unroll
    for (int mi = 0; mi < 4; ++mi)
      #pragma unroll
      for (int ni = 0; ni < 4; ++ni)
        acc[mi][ni] = __builtin_amdgcn_mfma_f32_16x16x32_bf16(bf[ni], af[mi], acc[mi][ni], 0, 0, 0);
  }

  const int cq = (lane >> 4) * 4;
  #pragma unroll
  for (int mi = 0; mi < 4; ++mi) {
    const int r = row0 + wm * 64 + mi * 16 + frow;
    unsigned short* crow = C + (size_t)r * KD;
    #pragma unroll
    for (int ni = 0; ni < 4; ++ni) {
      const int c = n0 + wn * 64 + ni * 16 + cq;
      if (c < KD) {  // wave-uniform per fragment
        f4_t v = acc[mi][ni];
        const f4_t bb = *(const f4_t*)(bias + c);
        float v0 = fmaxf(v[0] + bb[0], 0.f);
        float v1 = fmaxf(v[1] + bb[1], 0.f);
        float v2 = fmaxf(v[2] + bb[2], 0.f);
        float v3 = fmaxf(v[3] + bb[3], 0.f);
        uint2 pk;
        pk.x = (unsigned int)f2bf(v0) | ((unsigned int)f2bf(v1) << 16);
        pk.y = (unsigned int)f2bf(v2) | ((unsigned int)f2bf(v3) << 16);
        *(uint2*)(crow + c) = pk;
      }
    }
  }
}

// ---------------- final layer: out = A @ W3 + b3 (N=16 padded, write 12 cols f32) ----------
__global__ __launch_bounds__(256) void gemm_out(
    const unsigned short* __restrict__ A, const unsigned short* __restrict__ WT3,
    const float* __restrict__ b3, float* __restrict__ out) {
  __shared__ unsigned short sA[128 * 32];
  __shared__ unsigned short sB[16 * 32];
  const int tid = threadIdx.x, lane = tid & 63, wid = tid >> 6;
  const int row0 = blockIdx.x * 128;
  const char* gA = (const char*)A + (size_t)row0 * (KD * 2);
  const char* gB = (const char*)WT3;
  const int frow = lane & 15, fk = (lane >> 4) * 8;

  f4_t acc[2] = {};

  for (int kt = 0; kt < 25; ++kt) {
    const int kb = kt * 64;
    __syncthreads();
    #pragma unroll
    for (int L = 0; L < 2; ++L) {
      const int segb = L * 256 + wid * 64;
      const int seg = segb + lane;
      GLDS16(gA + (size_t)(seg >> 2) * (KD * 2) + kb + (seg & 3) * 16, (char*)sA + segb * 16);
    }
    if (wid == 0) {
      const int seg = lane;  // 16 rows x 32 K = 64 x 16B
      GLDS16(gB + (size_t)(seg >> 2) * (KD * 2) + kb + (seg & 3) * 16, (char*)sB);
    }
    __syncthreads();
    const bf8_t bf = *(const bf8_t*)(sB + frow * 32 + fk);
    #pragma unroll
    for (int mi = 0; mi < 2; ++mi) {
      const bf8_t af = *(const bf8_t*)(sA + (wid * 32 + mi * 16 + frow) * 32 + fk);
      acc[mi] = __builtin_amdgcn_mfma_f32_16x16x32_bf16(bf, af, acc[mi], 0, 0, 0);
    }
  }

  const int cg = (lane >> 4) * 4;
  #pragma unroll
  for (int mi = 0; mi < 2; ++mi) {
    const int r = row0 + wid * 32 + mi * 16 + frow;
    if (r < NROWS && cg < 12) {
      f4_t v = acc[mi];
      const f4_t bb = *(const f4_t*)(b3 + cg);  // cg in {0,4,8}: reads b3[0..11]
      v += bb;
      *(f4_t*)(out + (size_t)r * 12 + cg) = v;
    }
  }
}

// ---------------- host ----------------
extern "C" void kernel_launch(void* const* d_in, const int* in_sizes, int n_in,
                              void* d_out, int out_size, void* d_ws, size_t ws_size,
                              hipStream_t stream) {
  const float* mixer    = (const float*)d_in[0];
  const float* features = (const float*)d_in[1];
  const int*   sg_batch = (const int*)d_in[2];
  const int*   sg_map   = (const int*)d_in[3];
  const float* W0 = (const float*)d_in[4];  const float* b0 = (const float*)d_in[5];
  const float* W1 = (const float*)d_in[6];  const float* b1 = (const float*)d_in[7];
  const float* W2 = (const float*)d_in[8];  const float* b2 = (const float*)d_in[9];
  const float* W3 = (const float*)d_in[10]; const float* b3 = (const float*)d_in[11];
  float* out = (float*)d_out;

  char* wsp = (char*)d_ws;
  auto alloc = [&](size_t bytes) { char* p = wsp; wsp += (bytes + 255) & ~(size_t)255; return p; };
  unsigned short* h0  = (unsigned short*)alloc((size_t)MPAD * KD * 2);   // 64.1 MB
  unsigned short* h1  = (unsigned short*)alloc((size_t)MPAD * KD * 2);   // 64.1 MB
  unsigned short* Wt1 = (unsigned short*)alloc((size_t)NPW * KD * 2);
  unsigned short* Wt2 = (unsigned short*)alloc((size_t)NPW * KD * 2);
  unsigned short* Wt3 = (unsigned short*)alloc((size_t)16 * KD * 2);
  unsigned short* WTB = (unsigned short*)alloc((size_t)NPW * KA0 * 2);
  float* bp0   = (float*)alloc(KD * 4);
  float* bp1   = (float*)alloc(KD * 4);
  float* bp2   = (float*)alloc(KD * 4);
  float* fW0   = (float*)alloc((size_t)128 * KD * 4);
  int* counts  = (int*)alloc(NSEG * 4);
  // Cff (20.5 MB f32) and Abuf (12.8 MB bf16) alias h1's space: both are dead
  // before the first write to h1 (layer-1 GEMM output).
  float* Cff = (float*)h1;
  unsigned short* Abuf = (unsigned short*)((char*)h1 + ((size_t)MPAD * 128 * 4 + 255 & ~(size_t)255));

  // segment counts
  k_zero<<<(NSEG + 255) / 256, 256, 0, stream>>>(counts);
  k_count<<<(EN + 255) / 256, 256, 0, stream>>>(sg_map, counts);

  // Cf coefficient matrix
  k_zerof<<<(MPAD * 128 + 255) / 256, 256, 0, stream>>>(Cff, MPAD * 128);
  k_scatterCf<<<(EN + 255) / 256, 256, 0, stream>>>(sg_map, sg_batch, Cff);

  // weight prep
  k_flatW0<<<dim3(13, 16), 256, 0, stream>>>(mixer, W0, fW0);
  k_tpad<<<(NPW * KD + 255) / 256, 256, 0, stream>>>(W1, Wt1, 780, 780, NPW * KD);
  k_tpad<<<(NPW * KD + 255) / 256, 256, 0, stream>>>(W2, Wt2, 780, 780, NPW * KD);
  k_tpad<<<(16 * KD + 255) / 256, 256, 0, stream>>>(W3, Wt3, 12, 12, 16 * KD);
  k_padbias3<<<(3 * KD + 255) / 256, 256, 0, stream>>>(b0, b1, b2, bp0, bp1, bp2);
  k_buildB<<<(NPW * KA0 + 255) / 256, 256, 0, stream>>>(W0, fW0, WTB);

  // layer-0 operand A = [features | Cf | 0]
  k_buildA<<<(MPAD * KA0 + 255) / 256, 256, 0, stream>>>(features, counts, Cff, Abuf);

  // layer 0 as GEMM (K=160) -> h0
  gemm_relu<KA0><<<dim3(MPAD / 128, NPW / 128), 256, 0, stream>>>(Abuf, WTB, bp0, h0);

  // layers 1,2 (dense bf16 MFMA, K=800) -> h1 -> h0
  gemm_relu<KD><<<dim3(MPAD / 128, NPW / 128), 256, 0, stream>>>(h0, Wt1, bp1, h1);
  gemm_relu<KD><<<dim3(MPAD / 128, NPW / 128), 256, 0, stream>>>(h1, Wt2, bp2, h0);

  // layer 3 -> out
  gemm_out<<<MPAD / 128, 256, 0, stream>>>(h0, Wt3, b3, out);
}

// Round 7
// 379.979 us; speedup vs baseline: 2.0987x; 1.0703x over previous
//
#include <hip/hip_runtime.h>

// Problem constants (fixed by setup_inputs)
#define BG    4        // num_graphs
#define TT    12       // timesteps
#define NN    10000    // nodes per graph
#define EN    200000   // membership entries
#define NSEG  40000    // n*B segments
#define NROWS 40000    // B*n output rows
#define MPAD  40064    // 313*128
#define KD    800      // padded in_dim (780 -> 800 = 25*32)
#define KA0   160      // padded K for layer0 GEMM: 12 features + 128 Cf + 20 zero
#define NPW   896      // padded N for weight tiles (7*128)
#define NT    7        // N-tiles per row panel (NPW/128)

typedef __attribute__((ext_vector_type(8))) short bf8_t;   // 8 bf16 (4 VGPR) MFMA A/B frag
typedef __attribute__((ext_vector_type(4))) float f4_t;    // 4 f32 MFMA C/D frag

__device__ __forceinline__ unsigned short f2bf(float x) {  // RNE f32->bf16
  unsigned int u = __float_as_uint(x);
  u += 0x7fffu + ((u >> 16) & 1u);
  return (unsigned short)(u >> 16);
}

#define GLDS16(src, dst) __builtin_amdgcn_global_load_lds( \
    (const __attribute__((address_space(1))) void*)(src),  \
    (__attribute__((address_space(3))) void*)(dst), 16, 0, 0)

// ---------------- prep ----------------
__global__ void k_zero(int* counts) {
  int i = blockIdx.x * 256 + threadIdx.x;
  if (i < NSEG) counts[i] = 0;
}

__global__ void k_count(const int* __restrict__ mapper, int* __restrict__ counts) {
  int e = blockIdx.x * 256 + threadIdx.x;
  if (e < EN) atomicAdd(&counts[mapper[e]], 1);
}

__global__ void k_zerof(float* __restrict__ p, int n) {
  int i = blockIdx.x * 256 + threadIdx.x;
  if (i < n) p[i] = 0.f;
}

// Cf scatter: entry e contributes 1 to Cff[r][batch[e]], r = output row of segment mapper[e]
__global__ void k_scatterCf(const int* __restrict__ mapper, const int* __restrict__ batch,
                            float* __restrict__ Cff) {
  int e = blockIdx.x * 256 + threadIdx.x;
  if (e < EN) {
    const int s = mapper[e];
    const int r = (s % BG) * NN + s / BG;   // inverse of s = (r%NN)*BG + r/NN
    atomicAdd(&Cff[(size_t)r * 128 + batch[e]], 1.0f);
  }
}

// A = [features(12) | Cf(128) | 0(20)] as bf16, [MPAD][KA0]
__global__ void k_buildA(const float* __restrict__ features, const int* __restrict__ counts,
                         const float* __restrict__ Cff, unsigned short* __restrict__ A) {
  int idx = blockIdx.x * 256 + threadIdx.x;
  if (idx >= MPAD * KA0) return;
  const int r = idx / KA0, c = idx - r * KA0;
  float v = 0.f;
  if (r < NROWS) {
    if (c < 12) {
      v = features[(size_t)r * TT + c];
    } else if (c < 140) {
      const int s = (r % NN) * BG + (r / NN);
      const int cnt = counts[s];
      const float inv = 1.f / (float)(cnt > 0 ? cnt : 1);
      v = Cff[(size_t)r * 128 + (c - 12)] * inv;
    }
  }
  A[idx] = f2bf(v);
}

// B^T for layer0 GEMM: WTB[n][k] = k<12 ? W0[k][n] : k<140 ? fW0[k-12][n] : 0; [NPW][KA0]
__global__ void k_buildB(const float* __restrict__ W0, const float* __restrict__ fW0,
                         unsigned short* __restrict__ WTB) {
  int idx = blockIdx.x * 256 + threadIdx.x;
  if (idx >= NPW * KA0) return;
  const int n = idx / KA0, k = idx - n * KA0;
  float v = 0.f;
  if (n < 780) {
    if (k < 12) v = W0[(size_t)k * 780 + n];
    else if (k < 140) v = fW0[(size_t)(k - 12) * KD + n];
  }
  WTB[idx] = f2bf(v);
}

// Wt[n][k] = W[k][n], zero-padded to [Nrows][KD] bf16. W is [780][ldw].
__global__ void k_tpad(const float* __restrict__ W, unsigned short* __restrict__ Wt,
                       int ldw, int nsrc, int total) {
  int idx = blockIdx.x * 256 + threadIdx.x;
  if (idx >= total) return;
  int n = idx / KD, k = idx % KD;
  float v = (n < nsrc && k < 780) ? W[k * ldw + n] : 0.f;
  Wt[idx] = f2bf(v);
}

// pad b0,b1,b2 -> bp0,bp1,bp2 (KD wide, zeros past 780)
__global__ void k_padbias3(const float* __restrict__ b0, const float* __restrict__ b1,
                           const float* __restrict__ b2, float* __restrict__ p0,
                           float* __restrict__ p1, float* __restrict__ p2) {
  int i = blockIdx.x * 256 + threadIdx.x;
  if (i >= 3 * KD) return;
  const int which = i / KD, c = i - which * KD;
  const float* src = which == 0 ? b0 : (which == 1 ? b1 : b2);
  float* dst = which == 0 ? p0 : (which == 1 ? p1 : p2);
  dst[c] = (c < 780) ? src[c] : 0.f;
}

// flatW0[j][c] = sum_k flat[j][k] * W0[12+k][c], j<128, c<780 (0 for 780<=c<800)
// flat[j][t*64+f] = mixer_x[j%4][t][j/4][f]
// Split-K f32: grid (13 c-tiles x 16 j-tiles), block 256 = 64 c-lanes x 4 k-splits.
__global__ __launch_bounds__(256) void k_flatW0(const float* __restrict__ mixer,
                                                const float* __restrict__ W0,
                                                float* __restrict__ fW0) {
  __shared__ float sA[8][768];       // 24 KB: 8 A-rows
  __shared__ float sRed[4][64][9];   // 9.2 KB, pad 9 -> conflict-free
  const int tid = threadIdx.x;
  const int c0 = blockIdx.x * 64, j0 = blockIdx.y * 8;
  for (int i = tid; i < 8 * 768; i += 256) {
    int jj = i / 768;
    int k = i - jj * 768;
    int j = j0 + jj;
    int tt = k >> 6, ff = k & 63;
    sA[jj][k] = mixer[(((j & 3) * TT + tt) * 32 + (j >> 2)) * 64 + ff];
  }
  __syncthreads();
  const int cc = tid & 63, ks = tid >> 6;
  const int c = c0 + cc;
  float acc[8] = {};
  if (c < 780) {
    const float* wp = W0 + (size_t)(12 + ks * 192) * 780 + c;
    #pragma unroll 4
    for (int k = ks * 192; k < ks * 192 + 192; ++k) {
      const float w = *wp; wp += 780;
      #pragma unroll
      for (int jj = 0; jj < 8; ++jj) acc[jj] = fmaf(sA[jj][k], w, acc[jj]);
    }
  }
  #pragma unroll
  for (int jj = 0; jj < 8; ++jj) sRed[ks][cc][jj] = acc[jj];
  __syncthreads();
  for (int o = tid; o < 512; o += 256) {
    const int oc = o & 63, jj = o >> 6;
    const int wc = c0 + oc;
    if (wc < KD) {
      float s = sRed[0][oc][jj] + sRed[1][oc][jj] + sRed[2][oc][jj] + sRed[3][oc][jj];
      fW0[(size_t)(j0 + jj) * KD + wc] = s;  // cols >=780 stayed 0
    }
  }
}

// ---------------- dense layers: C = relu(A @ W + b), bf16 MFMA ----------------
// A [MPAD][KA] bf16, WT [*][KA] bf16, C [MPAD][KD] bf16 (output stride always KD).
// m97 structure: 128x128 tile, BK=32, 4 waves (2x2), global_load_lds w=16.
// SWAPPED operands: mfma(Wfrag, Afrag, acc) -> lane holds 4 consecutive output
// COLUMNS (packed 8B bf16 stores) at output row = lane&15.
// R6: 1D grid + bijective XCD swizzle (m204); n-tile innermost so the NT=7
// blocks sharing one A row-panel are consecutive on ONE XCD -> A-panel is
// fetched from HBM once and L2-hit 6 times (T1 mechanism).
template<int KA>
__global__ __launch_bounds__(256) void gemm_relu(
    const unsigned short* __restrict__ A, const unsigned short* __restrict__ WT,
    const float* __restrict__ bias, unsigned short* __restrict__ C) {
  __shared__ unsigned short sA[128 * 32];
  __shared__ unsigned short sB[128 * 32];
  const int tid = threadIdx.x, lane = tid & 63, wid = tid >> 6;
  const int wm = wid >> 1, wn = wid & 1;

  // bijective XCD swizzle (nwg = 313*NT = 2191)
  const int nwg = gridDim.x;
  const int q = nwg >> 3, r8 = nwg & 7;
  const int xcd = blockIdx.x & 7, idx = blockIdx.x >> 3;
  const int linear = (xcd < r8 ? xcd * (q + 1) : r8 * (q + 1) + (xcd - r8) * q) + idx;
  const int rowtile = linear / NT, ntile = linear - rowtile * NT;

  const int row0 = rowtile * 128, n0 = ntile * 128;
  const char* gA = (const char*)A + (size_t)row0 * (KA * 2);
  const char* gB = (const char*)WT + (size_t)n0 * (KA * 2);
  const int frow = lane & 15, fk = (lane >> 4) * 8;

  f4_t acc[4][4] = {};

  for (int kt = 0; kt < KA / 32; ++kt) {
    const int kb = kt * 64;  // byte offset of 32-element K chunk
    __syncthreads();
    #pragma unroll
    for (int L = 0; L < 2; ++L) {
      const int segb = L * 256 + wid * 64;
      const int seg = segb + lane;
      const size_t go = (size_t)(seg >> 2) * (KA * 2) + kb + (seg & 3) * 16;
      GLDS16(gA + go, (char*)sA + segb * 16);
      GLDS16(gB + go, (char*)sB + segb * 16);
    }
    __syncthreads();
    bf8_t af[4], bf[4];
    #pragma unroll
    for (int mi = 0; mi < 4; ++mi)
      af[mi] = *(const bf8_t*)(sA + (wm * 64 + mi * 16 + frow) * 32 + fk);
    #pragma unroll
    for (int ni = 0; ni < 4; ++ni)
      bf[ni] = *(const bf8_t*)(sB + (wn * 64 + ni * 16 + frow) * 32 + fk);
    #pragma unroll
    for (int mi = 0; mi < 4; ++mi)
      #pragma unroll
      for (int ni = 0; ni < 4; ++ni)
        acc[mi][ni] = __builtin_amdgcn_mfma_f32_16x16x32_bf16(bf[ni], af[mi], acc[mi][ni], 0, 0, 0);
  }

  const int cq = (lane >> 4) * 4;
  #pragma unroll
  for (int mi = 0; mi < 4; ++mi) {
    const int r = row0 + wm * 64 + mi * 16 + frow;
    unsigned short* crow = C + (size_t)r * KD;
    #pragma unroll
    for (int ni = 0; ni < 4; ++ni) {
      const int c = n0 + wn * 64 + ni * 16 + cq;
      if (c < KD) {  // wave-uniform per fragment
        f4_t v = acc[mi][ni];
        const f4_t bb = *(const f4_t*)(bias + c);
        float v0 = fmaxf(v[0] + bb[0], 0.f);
        float v1 = fmaxf(v[1] + bb[1], 0.f);
        float v2 = fmaxf(v[2] + bb[2], 0.f);
        float v3 = fmaxf(v[3] + bb[3], 0.f);
        uint2 pk;
        pk.x = (unsigned int)f2bf(v0) | ((unsigned int)f2bf(v1) << 16);
        pk.y = (unsigned int)f2bf(v2) | ((unsigned int)f2bf(v3) << 16);
        *(uint2*)(crow + c) = pk;
      }
    }
  }
}

// ---------------- final layer: out = A @ W3 + b3 (N=16 padded, write 12 cols f32) ----------
__global__ __launch_bounds__(256) void gemm_out(
    const unsigned short* __restrict__ A, const unsigned short* __restrict__ WT3,
    const float* __restrict__ b3, float* __restrict__ out) {
  __shared__ unsigned short sA[128 * 32];
  __shared__ unsigned short sB[16 * 32];
  const int tid = threadIdx.x, lane = tid & 63, wid = tid >> 6;
  const int row0 = blockIdx.x * 128;
  const char* gA = (const char*)A + (size_t)row0 * (KD * 2);
  const char* gB = (const char*)WT3;
  const int frow = lane & 15, fk = (lane >> 4) * 8;

  f4_t acc[2] = {};

  for (int kt = 0; kt < 25; ++kt) {
    const int kb = kt * 64;
    __syncthreads();
    #pragma unroll
    for (int L = 0; L < 2; ++L) {
      const int segb = L * 256 + wid * 64;
      const int seg = segb + lane;
      GLDS16(gA + (size_t)(seg >> 2) * (KD * 2) + kb + (seg & 3) * 16, (char*)sA + segb * 16);
    }
    if (wid == 0) {
      const int seg = lane;  // 16 rows x 32 K = 64 x 16B
      GLDS16(gB + (size_t)(seg >> 2) * (KD * 2) + kb + (seg & 3) * 16, (char*)sB);
    }
    __syncthreads();
    const bf8_t bf = *(const bf8_t*)(sB + frow * 32 + fk);
    #pragma unroll
    for (int mi = 0; mi < 2; ++mi) {
      const bf8_t af = *(const bf8_t*)(sA + (wid * 32 + mi * 16 + frow) * 32 + fk);
      acc[mi] = __builtin_amdgcn_mfma_f32_16x16x32_bf16(bf, af, acc[mi], 0, 0, 0);
    }
  }

  const int cg = (lane >> 4) * 4;
  #pragma unroll
  for (int mi = 0; mi < 2; ++mi) {
    const int r = row0 + wid * 32 + mi * 16 + frow;
    if (r < NROWS && cg < 12) {
      f4_t v = acc[mi];
      const f4_t bb = *(const f4_t*)(b3 + cg);  // cg in {0,4,8}: reads b3[0..11]
      v += bb;
      *(f4_t*)(out + (size_t)r * 12 + cg) = v;
    }
  }
}

// ---------------- host ----------------
extern "C" void kernel_launch(void* const* d_in, const int* in_sizes, int n_in,
                              void* d_out, int out_size, void* d_ws, size_t ws_size,
                              hipStream_t stream) {
  const float* mixer    = (const float*)d_in[0];
  const float* features = (const float*)d_in[1];
  const int*   sg_batch = (const int*)d_in[2];
  const int*   sg_map   = (const int*)d_in[3];
  const float* W0 = (const float*)d_in[4];  const float* b0 = (const float*)d_in[5];
  const float* W1 = (const float*)d_in[6];  const float* b1 = (const float*)d_in[7];
  const float* W2 = (const float*)d_in[8];  const float* b2 = (const float*)d_in[9];
  const float* W3 = (const float*)d_in[10]; const float* b3 = (const float*)d_in[11];
  float* out = (float*)d_out;

  char* wsp = (char*)d_ws;
  auto alloc = [&](size_t bytes) { char* p = wsp; wsp += (bytes + 255) & ~(size_t)255; return p; };
  unsigned short* h0  = (unsigned short*)alloc((size_t)MPAD * KD * 2);   // 64.1 MB
  unsigned short* h1  = (unsigned short*)alloc((size_t)MPAD * KD * 2);   // 64.1 MB
  unsigned short* Wt1 = (unsigned short*)alloc((size_t)NPW * KD * 2);
  unsigned short* Wt2 = (unsigned short*)alloc((size_t)NPW * KD * 2);
  unsigned short* Wt3 = (unsigned short*)alloc((size_t)16 * KD * 2);
  unsigned short* WTB = (unsigned short*)alloc((size_t)NPW * KA0 * 2);
  float* bp0   = (float*)alloc(KD * 4);
  float* bp1   = (float*)alloc(KD * 4);
  float* bp2   = (float*)alloc(KD * 4);
  float* fW0   = (float*)alloc((size_t)128 * KD * 4);
  int* counts  = (int*)alloc(NSEG * 4);
  // Cff (20.5 MB f32) and Abuf (12.8 MB bf16) alias h1's space: both are dead
  // before the first write to h1 (layer-1 GEMM output).
  float* Cff = (float*)h1;
  unsigned short* Abuf = (unsigned short*)((char*)h1 + ((size_t)MPAD * 128 * 4 + 255 & ~(size_t)255));

  // segment counts
  k_zero<<<(NSEG + 255) / 256, 256, 0, stream>>>(counts);
  k_count<<<(EN + 255) / 256, 256, 0, stream>>>(sg_map, counts);

  // Cf coefficient matrix
  k_zerof<<<(MPAD * 128 + 255) / 256, 256, 0, stream>>>(Cff, MPAD * 128);
  k_scatterCf<<<(EN + 255) / 256, 256, 0, stream>>>(sg_map, sg_batch, Cff);

  // weight prep
  k_flatW0<<<dim3(13, 16), 256, 0, stream>>>(mixer, W0, fW0);
  k_tpad<<<(NPW * KD + 255) / 256, 256, 0, stream>>>(W1, Wt1, 780, 780, NPW * KD);
  k_tpad<<<(NPW * KD + 255) / 256, 256, 0, stream>>>(W2, Wt2, 780, 780, NPW * KD);
  k_tpad<<<(16 * KD + 255) / 256, 256, 0, stream>>>(W3, Wt3, 12, 12, 16 * KD);
  k_padbias3<<<(3 * KD + 255) / 256, 256, 0, stream>>>(b0, b1, b2, bp0, bp1, bp2);
  k_buildB<<<(NPW * KA0 + 255) / 256, 256, 0, stream>>>(W0, fW0, WTB);

  // layer-0 operand A = [features | Cf | 0]
  k_buildA<<<(MPAD * KA0 + 255) / 256, 256, 0, stream>>>(features, counts, Cff, Abuf);

  // layer 0 as GEMM (K=160) -> h0
  gemm_relu<KA0><<<(MPAD / 128) * NT, 256, 0, stream>>>(Abuf, WTB, bp0, h0);

  // layers 1,2 (dense bf16 MFMA, K=800) -> h1 -> h0
  gemm_relu<KD><<<(MPAD / 128) * NT, 256, 0, stream>>>(h0, Wt1, bp1, h1);
  gemm_relu<KD><<<(MPAD / 128) * NT, 256, 0, stream>>>(h1, Wt2, bp2, h0);

  // layer 3 -> out
  gemm_out<<<MPAD / 128, 256, 0, stream>>>(h0, Wt3, b3, out);
}